// Round 7
// baseline (282.014 us; speedup 1.0000x reference)
//
#include <hip/hip_runtime.h>
#include <math.h>

#define NCOMP 32768
#define LDIM  128
#define HDIM  512
#define DDIM  256
#define BROWS 512
#define KTOP  16

// -0.5 * D * log(2*pi)
#define NEG_HALF_D_LOG2PI (-235.24844f)

typedef short bf16x8 __attribute__((ext_vector_type(8)));
typedef float f32x4  __attribute__((ext_vector_type(4)));
typedef unsigned short ushort_t;
typedef unsigned int uint_t;
typedef unsigned long long u64_t;

// ---------------- bf16 helpers (RNE) ----------------
__device__ __forceinline__ ushort_t f2bf(float f) {
  uint_t u = __float_as_uint(f);
  u = u + 0x7fffu + ((u >> 16) & 1u);
  return (ushort_t)(u >> 16);
}
__device__ __forceinline__ float bf2f(ushort_t h) {
  return __uint_as_float(((uint_t)h) << 16);
}

// async global->LDS, 16B per lane. LDS dest is wave-uniform base + lane*16.
__device__ __forceinline__ void load_lds16(const ushort_t* g, ushort_t* l) {
  __builtin_amdgcn_global_load_lds(
      (const __attribute__((address_space(1))) unsigned int*)g,
      (__attribute__((address_space(3))) unsigned int*)l, 16, 0, 0);
}

#define BAR()   do { __builtin_amdgcn_sched_barrier(0); __builtin_amdgcn_s_barrier(); __builtin_amdgcn_sched_barrier(0); } while (0)
#define LGKM0() do { asm volatile("s_waitcnt lgkmcnt(0)" ::: "memory"); __builtin_amdgcn_sched_barrier(0); } while (0)
#define VMCNT(n) do { asm volatile("s_waitcnt vmcnt(" #n ")" ::: "memory"); __builtin_amdgcn_sched_barrier(0); } while (0)

// ------------------------------------------------------------------
// Prep kernels
// ------------------------------------------------------------------
__global__ __launch_bounds__(256) void cast_z_kernel(const float* __restrict__ z,
                                                     ushort_t* __restrict__ z16) {
  int i = (blockIdx.x * 256 + threadIdx.x) * 4;   // over 32768*128
  float4 v = *(const float4*)&z[i];
  z16[i + 0] = f2bf(v.x);
  z16[i + 1] = f2bf(v.y);
  z16[i + 2] = f2bf(v.z);
  z16[i + 3] = f2bf(v.w);
}

// W [R][512] fp32 -> Wt [512][R] bf16
__global__ __launch_bounds__(256) void transpose_cast_kernel(const float* __restrict__ W,
                                                             ushort_t* __restrict__ Wt,
                                                             int R) {
  int i = blockIdx.x * 256 + threadIdx.x;  // R*512
  int r = i >> 9, c = i & 511;
  Wt[(size_t)c * R + r] = f2bf(W[i]);
}

// Xs [512][1536] bf16 : [hi(u) | lo(u) | hi(u)], u = [x^2 (256), x (256)]
__global__ __launch_bounds__(256) void xprime_split_kernel(const float* __restrict__ x,
                                                           ushort_t* __restrict__ Xs) {
  int i = blockIdx.x * 256 + threadIdx.x;   // 512*256
  int b = i >> 8, d = i & 255;
  float xv = x[i];
  float x2 = xv * xv;
  ushort_t h2 = f2bf(x2), h1 = f2bf(xv);
  float l2 = x2 - bf2f(h2), l1 = xv - bf2f(h1);
  size_t base = (size_t)b * 1536;
  Xs[base + d]        = h2;
  Xs[base + 256 + d]  = h1;
  Xs[base + 512 + d]  = f2bf(l2);
  Xs[base + 768 + d]  = f2bf(l1);
  Xs[base + 1024 + d] = h2;
  Xs[base + 1280 + d] = h1;
}

// raw [N][512] fp32 (mu | logvar) -> Ps [N][1024] bf16 : [hi(v) | lo(v)],
// v = [-0.5*inv_var (256), mu*inv_var (256)], plus cvec [N].
__global__ __launch_bounds__(256) void params_kernel(const float* __restrict__ raw,
                                                     ushort_t* __restrict__ Ps,
                                                     float* __restrict__ cvec) {
  const int w = threadIdx.x >> 6, lane = threadIdx.x & 63;
  const int n = blockIdx.x * 4 + w;
  size_t rb = (size_t)n * 512;
  float4 mu4 = *(const float4*)(raw + rb + lane * 4);
  float4 lv4 = *(const float4*)(raw + rb + 256 + lane * 4);
  float mus[4] = {mu4.x, mu4.y, mu4.z, mu4.w};
  float lvs[4] = {lv4.x, lv4.y, lv4.z, lv4.w};
  ushort4 o0, o1, o2, o3;
  ushort_t* p0 = &o0.x; ushort_t* p1 = &o1.x;
  ushort_t* p2 = &o2.x; ushort_t* p3 = &o3.x;
  float part = 0.f;
  #pragma unroll
  for (int e = 0; e < 4; e++) {
    float lv = lvs[e];
    float sp = (lv > 20.f) ? lv : log1pf(expf(lv));
    float sd = fminf(sp + 0.1f, 1.0f);
    float iv = 1.0f / (sd * sd);
    float v0 = -0.5f * iv;
    float v1 = mus[e] * iv;
    ushort_t h0 = f2bf(v0), h1 = f2bf(v1);
    p0[e] = h0; p1[e] = h1;
    p2[e] = f2bf(v0 - bf2f(h0));
    p3[e] = f2bf(v1 - bf2f(h1));
    part += -0.5f * mus[e] * mus[e] * iv - logf(sd);
  }
  size_t pb = (size_t)n * 1024;
  *(ushort4*)(Ps + pb + lane * 4)       = o0;
  *(ushort4*)(Ps + pb + 256 + lane * 4) = o1;
  *(ushort4*)(Ps + pb + 512 + lane * 4) = o2;
  *(ushort4*)(Ps + pb + 768 + lane * 4) = o3;
  #pragma unroll
  for (int off = 32; off > 0; off >>= 1) part += __shfl_down(part, off, 64);
  if (lane == 0) cvec[n] = part + NEG_HALF_D_LOG2PI;
}

// ------------------------------------------------------------------
// 256x256 bf16 MFMA GEMM, 8-phase schedule with counted vmcnt (T3+T4+T5).
// BK=64 K-tiles; per tile 4 phases, each: {ds_read quadrant frags | stage
// one half-tile} -> s_barrier -> lgkmcnt(0) -> 16 MFMA -> s_barrier.
// vmcnt(4) only at each tile's last phase (2 half-tiles stay in flight).
// Stage order (B0,A0 two tiles ahead; A1,B1 one tile ahead) guarantees a
// buffer region is re-staged only >=1 phase after its last ds_read:
//   tile t phases stage H(6+4t..9+4t); H(j): tile j>>2, sub j&3 ->
//   {0:B-half0, 1:A-half0, 2:A-half1, 3:B-half1}.
// Quadrant order: (mh0,nh0) (mh0,nh1) (mh1,nh1) (mh1,nh0) so A regs are
// reloaded once and both B reg-sets live across the tile.
// Epilogue: vmcnt(0) once t+2 >= nt.
// ------------------------------------------------------------------
template<int EPI>
__global__ __launch_bounds__(512, 2) void gemm256(
    const ushort_t* __restrict__ A, int lda,
    const ushort_t* __restrict__ B, int ldb,
    const float* __restrict__ bias,
    void* __restrict__ Cout, int ldc,
    int nt, int sps,
    int kbA0, int kbA1, int kbA2,
    int kbB0, int kbB1, int kbB2,
    int nShort, int shortIsM) {
  __shared__ __align__(16) ushort_t As[2][16384];   // 32KB per buffer
  __shared__ __align__(16) ushort_t Bs[2][16384];

  const int tid = threadIdx.x;
  const int lane = tid & 63, wid = tid >> 6;
  const int wr = wid >> 2, wc = wid & 3;            // 2 x 4 wave grid

  // XCD-chunked bijective block swizzle (gridDim.x % 8 == 0)
  const int cpx = gridDim.x >> 3;
  const int newid = (blockIdx.x & 7) * cpx + (blockIdx.x >> 3);
  const int s = newid % nShort, l = newid / nShort;
  const int m0 = (shortIsM ? s : l) * 256;
  const int n0 = (shortIsM ? l : s) * 256;

  // ---- staging geometry: thread covers chunks {half*1024 + tid, +512} ----
  const int row_r0 = tid >> 3;            // 0..63
  const int row_r1 = 64 + row_r0;         // 64..127
  const int col_s = ((tid & 7) ^ (row_r0 & 7)) * 8;  // inverse-swizzled col

  // ---- fragment read byte-offsets (swizzled); k-half composed via XOR ----
  int aoff[8], boff[4];
  #pragma unroll
  for (int i = 0; i < 8; i++) {
    int ra = wr * 128 + i * 16 + (lane & 15);
    aoff[i] = (ra * 128 + ((lane >> 4) * 16)) ^ ((ra & 7) << 4);
  }
  #pragma unroll
  for (int j = 0; j < 4; j++) {
    int rb = wc * 64 + j * 16 + (lane & 15);
    boff[j] = (rb * 128 + ((lane >> 4) * 16)) ^ ((rb & 7) << 4);
  }

  f32x4 acc[8][4];
  #pragma unroll
  for (int i = 0; i < 8; i++)
    #pragma unroll
    for (int j = 0; j < 4; j++)
      acc[i][j] = (f32x4){0.f, 0.f, 0.f, 0.f};

  bf16x8 aR[4][2], bR0[2][2], bR1[2][2];

  // stage half-tile by global H-index j (see header comment)
  auto stageH = [&](int j) {
    int t = j >> 2;
    if (t >= nt) return;
    int sub = j & 3;
    int q = (sub == 0) ? 1 : (sub == 1) ? 0 : sub;   // ->{B0,A0,A1,B1}
    int bb = t & 1;
    int sg = (t >= sps) ? ((t >= 2 * sps) ? 2 : 1) : 0;
    int ks = (t - sg * sps) << 6;
    int half = q >> 1;
    if ((q & 1) == 0) {   // A halves (q=0,2)
      int kA = ((sg == 0) ? kbA0 : (sg == 1) ? kbA1 : kbA2) + ks;
      const ushort_t* s0 = A + (size_t)(m0 + half * 128 + row_r0) * lda + col_s + kA;
      const ushort_t* s1 = A + (size_t)(m0 + half * 128 + row_r1) * lda + col_s + kA;
      load_lds16(s0, &As[bb][(half * 1024 + tid) * 8]);
      load_lds16(s1, &As[bb][(half * 1024 + 512 + tid) * 8]);
    } else {              // B halves (q=1,3)
      int kB = ((sg == 0) ? kbB0 : (sg == 1) ? kbB1 : kbB2) + ks;
      const ushort_t* s0 = B + (size_t)(n0 + half * 128 + row_r0) * ldb + col_s + kB;
      const ushort_t* s1 = B + (size_t)(n0 + half * 128 + row_r1) * ldb + col_s + kB;
      load_lds16(s0, &Bs[bb][(half * 1024 + tid) * 8]);
      load_lds16(s1, &Bs[bb][(half * 1024 + 512 + tid) * 8]);
    }
  };

  // ---- prologue: stage H0..H5 (tile0 complete + tile1 B0,A0) ----
  for (int j = 0; j < 6; ++j) stageH(j);
  VMCNT(4);                      // tile0's 8 loads landed; 4 in flight
  BAR();

  int hctr = 6;
  for (int t = 0; t < nt; ++t) {
    const int bb = t & 1;
    const char* Ab = (const char*)(&As[0][0]) + bb * 32768;
    const char* Bb = (const char*)(&Bs[0][0]) + bb * 32768;

    // ---- P0: read A[mh0]+B[nh0], stage, MFMA (mh0,nh0) ----
    #pragma unroll
    for (int i2 = 0; i2 < 4; i2++)
      #pragma unroll
      for (int kh = 0; kh < 2; kh++)
        aR[i2][kh] = *(const bf16x8*)(Ab + (aoff[i2] ^ (kh << 6)));
    #pragma unroll
    for (int j2 = 0; j2 < 2; j2++)
      #pragma unroll
      for (int kh = 0; kh < 2; kh++)
        bR0[j2][kh] = *(const bf16x8*)(Bb + (boff[j2] ^ (kh << 6)));
    stageH(hctr + 0);
    BAR(); LGKM0();
    __builtin_amdgcn_s_setprio(1);
    #pragma unroll
    for (int kh = 0; kh < 2; kh++)
      #pragma unroll
      for (int i2 = 0; i2 < 4; i2++)
        #pragma unroll
        for (int j2 = 0; j2 < 2; j2++)
          acc[i2][j2] = __builtin_amdgcn_mfma_f32_16x16x32_bf16(aR[i2][kh], bR0[j2][kh], acc[i2][j2], 0, 0, 0);
    __builtin_amdgcn_s_setprio(0);
    BAR();

    // ---- P1: read B[nh1], stage, MFMA (mh0,nh1) ----
    #pragma unroll
    for (int j2 = 0; j2 < 2; j2++)
      #pragma unroll
      for (int kh = 0; kh < 2; kh++)
        bR1[j2][kh] = *(const bf16x8*)(Bb + (boff[2 + j2] ^ (kh << 6)));
    stageH(hctr + 1);
    BAR(); LGKM0();
    __builtin_amdgcn_s_setprio(1);
    #pragma unroll
    for (int kh = 0; kh < 2; kh++)
      #pragma unroll
      for (int i2 = 0; i2 < 4; i2++)
        #pragma unroll
        for (int j2 = 0; j2 < 2; j2++)
          acc[i2][2 + j2] = __builtin_amdgcn_mfma_f32_16x16x32_bf16(aR[i2][kh], bR1[j2][kh], acc[i2][2 + j2], 0, 0, 0);
    __builtin_amdgcn_s_setprio(0);
    BAR();

    // ---- P2: read A[mh1], stage, MFMA (mh1,nh1) ----
    #pragma unroll
    for (int i2 = 0; i2 < 4; i2++)
      #pragma unroll
      for (int kh = 0; kh < 2; kh++)
        aR[i2][kh] = *(const bf16x8*)(Ab + (aoff[4 + i2] ^ (kh << 6)));
    stageH(hctr + 2);
    BAR(); LGKM0();
    __builtin_amdgcn_s_setprio(1);
    #pragma unroll
    for (int kh = 0; kh < 2; kh++)
      #pragma unroll
      for (int i2 = 0; i2 < 4; i2++)
        #pragma unroll
        for (int j2 = 0; j2 < 2; j2++)
          acc[4 + i2][2 + j2] = __builtin_amdgcn_mfma_f32_16x16x32_bf16(aR[i2][kh], bR1[j2][kh], acc[4 + i2][2 + j2], 0, 0, 0);
    __builtin_amdgcn_s_setprio(0);
    BAR();

    // ---- P3: stage, MFMA (mh1,nh0), counted vmcnt ----
    stageH(hctr + 3);
    BAR();
    __builtin_amdgcn_s_setprio(1);
    #pragma unroll
    for (int kh = 0; kh < 2; kh++)
      #pragma unroll
      for (int i2 = 0; i2 < 4; i2++)
        #pragma unroll
        for (int j2 = 0; j2 < 2; j2++)
          acc[4 + i2][j2] = __builtin_amdgcn_mfma_f32_16x16x32_bf16(aR[i2][kh], bR0[j2][kh], acc[4 + i2][j2], 0, 0, 0);
    __builtin_amdgcn_s_setprio(0);
    if (t + 2 < nt) { VMCNT(4); } else { VMCNT(0); }
    BAR();

    hctr += 4;
  }

  // ---- epilogue ----
  float bv[4];
  #pragma unroll
  for (int j = 0; j < 4; j++)
    bv[j] = bias[n0 + wc * 64 + j * 16 + (lane & 15)];
  #pragma unroll
  for (int i = 0; i < 8; i++) {
    int rowb = m0 + wr * 128 + i * 16 + ((lane >> 4) << 2);
    #pragma unroll
    for (int r = 0; r < 4; r++) {
      #pragma unroll
      for (int j = 0; j < 4; j++) {
        int col = n0 + wc * 64 + j * 16 + (lane & 15);
        float v = acc[i][j][r] + bv[j];
        if (EPI == 0) {
          v = fmaxf(v, 0.f);
          ((ushort_t*)Cout)[(size_t)(rowb + r) * ldc + col] = f2bf(v);
        } else {
          ((float*)Cout)[(size_t)(rowb + r) * ldc + col] = v;
        }
      }
    }
  }
}

// ------------------------------------------------------------------
// Top-16: wave-cooperative ballot-filtered select (unchanged, verified).
// ------------------------------------------------------------------
__device__ __forceinline__ u64_t shfl_up1_u64(u64_t v) {
  uint_t lo = (uint_t)v, hi = (uint_t)(v >> 32);
  lo = __shfl_up(lo, 1, 64); hi = __shfl_up(hi, 1, 64);
  return ((u64_t)hi << 32) | lo;
}
__device__ __forceinline__ u64_t shfl_u64(u64_t v, int src) {
  uint_t lo = (uint_t)v, hi = (uint_t)(v >> 32);
  lo = __shfl(lo, src, 64); hi = __shfl(hi, src, 64);
  return ((u64_t)hi << 32) | lo;
}
__device__ __forceinline__ void insert_step(u64_t& key, u64_t cand, int lane) {
  u64_t kup = shfl_up1_u64(key);
  if (lane == 0) kup = ~0ULL;
  if (cand > key) key = (cand > kup) ? kup : cand;
}

__global__ __launch_bounds__(256) void topk_kernel(const float* __restrict__ lp,
                                                   const float* __restrict__ log_w,
                                                   float* __restrict__ out) {
  const int b = blockIdx.x;
  const int tid = threadIdx.x;
  const int w = tid >> 6, lane = tid & 63;
  const float* row = lp + (size_t)b * NCOMP;

  u64_t key = 0;
  u64_t theta = 0;

  const int base = w * 8192;
  for (int c = 0; c < 32; ++c) {
    int n0 = base + c * 256 + lane * 4;
    float4 s4 = *(const float4*)&row[n0];
    float4 w4 = *(const float4*)&log_w[n0];
    float ss[4] = {s4.x + w4.x, s4.y + w4.y, s4.z + w4.z, s4.w + w4.w};
    #pragma unroll
    for (int e = 0; e < 4; e++) {
      uint_t u = __float_as_uint(ss[e]);
      u = (u & 0x80000000u) ? ~u : (u | 0x80000000u);
      u64_t k = ((u64_t)u << 32) | (u64_t)(0xFFFFFFFFu - (uint_t)(n0 + e));
      u64_t m = __ballot(k > theta);
      if (m) {
        do {
          int src = __ffsll((long long)m) - 1;
          m &= m - 1;
          u64_t cand = shfl_u64(k, src);
          insert_step(key, cand, lane);
        } while (m);
        theta = shfl_u64(key, 15);
      }
    }
  }

  __shared__ u64_t sk[64];
  if (lane < 16) sk[w * 16 + lane] = key;
  __syncthreads();
  if (w == 0) {
    u64_t th = shfl_u64(key, 15);
    for (int t = 16; t < 64; ++t) {
      u64_t cand = sk[t];
      if (cand > th) {
        insert_step(key, cand, lane);
        th = shfl_u64(key, 15);
      }
    }
    if (lane < 16) {
      uint_t idx = 0xFFFFFFFFu - (uint_t)key;
      out[(size_t)b * KTOP + lane] = row[idx];
    }
  }
}

// ------------------------------------------------------------------
extern "C" void kernel_launch(void* const* d_in, const int* in_sizes, int n_in,
                              void* d_out, int out_size, void* d_ws, size_t ws_size,
                              hipStream_t stream) {
  const float* x     = (const float*)d_in[0];
  const float* log_w = (const float*)d_in[1];
  const float* z     = (const float*)d_in[2];
  const float* W1    = (const float*)d_in[3];
  const float* b1    = (const float*)d_in[4];
  const float* W2    = (const float*)d_in[5];
  const float* b2    = (const float*)d_in[6];
  float* out = (float*)d_out;

  char* p = (char*)d_ws;
  float* raw   = (float*)p;    p += (size_t)NCOMP * 512 * 4;   // 64MB (reused as lp)
  float* cvec  = (float*)p;    p += (size_t)NCOMP * 4;
  ushort_t* Ps = (ushort_t*)p; p += (size_t)NCOMP * 1024 * 2;  // 64MB
  ushort_t* h16= (ushort_t*)p; p += (size_t)NCOMP * 512 * 2;   // 32MB
  ushort_t* z16= (ushort_t*)p; p += (size_t)NCOMP * 128 * 2;   // 8MB
  ushort_t* W1t= (ushort_t*)p; p += (size_t)512 * 128 * 2;
  ushort_t* W2t= (ushort_t*)p; p += (size_t)512 * 512 * 2;
  ushort_t* Xs = (ushort_t*)p; p += (size_t)512 * 1536 * 2;
  float* lp = raw;

  // prep
  hipLaunchKernelGGL(cast_z_kernel, dim3(NCOMP * LDIM / 1024), dim3(256), 0, stream, z, z16);
  hipLaunchKernelGGL(transpose_cast_kernel, dim3(LDIM * HDIM / 256), dim3(256), 0, stream, W1, W1t, LDIM);
  hipLaunchKernelGGL(transpose_cast_kernel, dim3(HDIM * HDIM / 256), dim3(256), 0, stream, W2, W2t, HDIM);
  hipLaunchKernelGGL(xprime_split_kernel, dim3(BROWS * DDIM / 256), dim3(256), 0, stream, x, Xs);

  // G1: h16 = relu(z16 @ W1t^T + b1)   [32768,128] x [512,128]^T, nt=2
  hipLaunchKernelGGL((gemm256<0>), dim3(256), dim3(512), 0, stream,
                     z16, LDIM, W1t, LDIM, b1, h16, HDIM,
                     2, 2, 0, 0, 0, 0, 0, 0, 2, 0);
  // G2: raw = h16 @ W2t^T + b2         [32768,512] x [512,512]^T, nt=8
  hipLaunchKernelGGL((gemm256<1>), dim3(256), dim3(512), 0, stream,
                     h16, HDIM, W2t, HDIM, b2, raw, HDIM,
                     8, 8, 0, 0, 0, 0, 0, 0, 2, 0);
  // params: raw -> Ps (split hi/lo), cvec
  hipLaunchKernelGGL(params_kernel, dim3(NCOMP / 4), dim3(256), 0, stream, raw, Ps, cvec);
  // G3: lp = Xs @ Ps^T + cvec  (split-bf16: hi*hi + lo*hi + hi*lo), nt=24
  hipLaunchKernelGGL((gemm256<1>), dim3(256), dim3(512), 0, stream,
                     Xs, 1536, Ps, 1024, cvec, lp, NCOMP,
                     24, 8, 0, 512, 1024, 0, 0, 512, 2, 1);
  // topk
  hipLaunchKernelGGL(topk_kernel, dim3(BROWS), dim3(256), 0, stream, lp, log_w, out);
}

// Round 8
// 212.767 us; speedup vs baseline: 1.3255x; 1.3255x over previous
//
#include <hip/hip_runtime.h>
#include <math.h>

#define NCOMP 32768
#define LDIM  128
#define HDIM  512
#define DDIM  256
#define BROWS 512
#define KTOP  16

// -0.5 * D * log(2*pi)
#define NEG_HALF_D_LOG2PI (-235.24844f)

typedef short bf16x8 __attribute__((ext_vector_type(8)));
typedef float f32x4  __attribute__((ext_vector_type(4)));
typedef unsigned short ushort_t;
typedef unsigned int uint_t;
typedef unsigned long long u64_t;

// ---------------- bf16 helpers (RNE) ----------------
__device__ __forceinline__ ushort_t f2bf(float f) {
  uint_t u = __float_as_uint(f);
  u = u + 0x7fffu + ((u >> 16) & 1u);
  return (ushort_t)(u >> 16);
}
__device__ __forceinline__ float bf2f(ushort_t h) {
  return __uint_as_float(((uint_t)h) << 16);
}

// async global->LDS, 16B per lane. LDS dest is wave-uniform base + lane*16.
__device__ __forceinline__ void load_lds16(const ushort_t* g, ushort_t* l) {
  __builtin_amdgcn_global_load_lds(
      (const __attribute__((address_space(1))) unsigned int*)g,
      (__attribute__((address_space(3))) unsigned int*)l, 16, 0, 0);
}

// ------------------------------------------------------------------
// Prep kernels
// ------------------------------------------------------------------
__global__ __launch_bounds__(256) void cast_z_kernel(const float* __restrict__ z,
                                                     ushort_t* __restrict__ z16) {
  int i = (blockIdx.x * 256 + threadIdx.x) * 4;   // over 32768*128
  float4 v = *(const float4*)&z[i];
  z16[i + 0] = f2bf(v.x);
  z16[i + 1] = f2bf(v.y);
  z16[i + 2] = f2bf(v.z);
  z16[i + 3] = f2bf(v.w);
}

// W [R][512] fp32 -> Wt [512][R] bf16
__global__ __launch_bounds__(256) void transpose_cast_kernel(const float* __restrict__ W,
                                                             ushort_t* __restrict__ Wt,
                                                             int R) {
  int i = blockIdx.x * 256 + threadIdx.x;  // R*512
  int r = i >> 9, c = i & 511;
  Wt[(size_t)c * R + r] = f2bf(W[i]);
}

// Xs [512][512] bf16 : hi(u), u = [x^2 (256), x (256)].
// (A-side lo term dropped: score = uh*(vh+vl), error ~2^-9*|u||v| sums.)
__global__ __launch_bounds__(256) void xprime_split_kernel(const float* __restrict__ x,
                                                           ushort_t* __restrict__ Xs) {
  int i = blockIdx.x * 256 + threadIdx.x;   // 512*256
  int b = i >> 8, d = i & 255;
  float xv = x[i];
  float x2 = xv * xv;
  size_t base = (size_t)b * 512;
  Xs[base + d]       = f2bf(x2);
  Xs[base + 256 + d] = f2bf(xv);
}

// raw [N][512] fp32 (mu | logvar) -> Ps [N][1024] bf16 : [hi(v) | lo(v)],
// v = [-0.5*inv_var (256), mu*inv_var (256)], plus cvec [N].
__global__ __launch_bounds__(256) void params_kernel(const float* __restrict__ raw,
                                                     ushort_t* __restrict__ Ps,
                                                     float* __restrict__ cvec) {
  const int w = threadIdx.x >> 6, lane = threadIdx.x & 63;
  const int n = blockIdx.x * 4 + w;
  size_t rb = (size_t)n * 512;
  float4 mu4 = *(const float4*)(raw + rb + lane * 4);
  float4 lv4 = *(const float4*)(raw + rb + 256 + lane * 4);
  float mus[4] = {mu4.x, mu4.y, mu4.z, mu4.w};
  float lvs[4] = {lv4.x, lv4.y, lv4.z, lv4.w};
  ushort4 o0, o1, o2, o3;
  ushort_t* p0 = &o0.x; ushort_t* p1 = &o1.x;
  ushort_t* p2 = &o2.x; ushort_t* p3 = &o3.x;
  float part = 0.f;
  #pragma unroll
  for (int e = 0; e < 4; e++) {
    float lv = lvs[e];
    float sp = (lv > 20.f) ? lv : log1pf(expf(lv));
    float sd = fminf(sp + 0.1f, 1.0f);
    float iv = 1.0f / (sd * sd);
    float v0 = -0.5f * iv;
    float v1 = mus[e] * iv;
    ushort_t h0 = f2bf(v0), h1 = f2bf(v1);
    p0[e] = h0; p1[e] = h1;
    p2[e] = f2bf(v0 - bf2f(h0));
    p3[e] = f2bf(v1 - bf2f(h1));
    part += -0.5f * mus[e] * mus[e] * iv - logf(sd);
  }
  size_t pb = (size_t)n * 1024;
  *(ushort4*)(Ps + pb + lane * 4)       = o0;
  *(ushort4*)(Ps + pb + 256 + lane * 4) = o1;
  *(ushort4*)(Ps + pb + 512 + lane * 4) = o2;
  *(ushort4*)(Ps + pb + 768 + lane * 4) = o3;
  #pragma unroll
  for (int off = 32; off > 0; off >>= 1) part += __shfl_down(part, off, 64);
  if (lane == 0) cvec[n] = part + NEG_HALF_D_LOG2PI;
}

// ------------------------------------------------------------------
// 256x256 bf16 MFMA GEMM — round-6 2-phase structure (proven).
// BK=64, 512 threads (8 waves 2x4), double-buffered 128KB LDS,
// global_load_lds 16B with pre-swizzled source, XOR swizzle, k-half
// composed via XOR. One __syncthreads per K-step.
// ------------------------------------------------------------------
template<int EPI>
__global__ __launch_bounds__(512, 2) void gemm256(
    const ushort_t* __restrict__ A, int lda,
    const ushort_t* __restrict__ B, int ldb,
    const float* __restrict__ bias,
    void* __restrict__ Cout, int ldc,
    int nsteps, int sps,
    int kbA0, int kbA1, int kbA2,
    int kbB0, int kbB1, int kbB2,
    int nShort, int shortIsM) {
  __shared__ __align__(16) ushort_t As[2][16384];   // 32KB per buffer
  __shared__ __align__(16) ushort_t Bs[2][16384];

  const int tid = threadIdx.x;
  const int lane = tid & 63, wid = tid >> 6;
  const int wr = wid >> 2, wc = wid & 3;            // 2 x 4 wave grid

  // XCD-chunked bijective block swizzle (gridDim.x % 8 == 0)
  const int cpx = gridDim.x >> 3;
  const int newid = (blockIdx.x & 7) * cpx + (blockIdx.x >> 3);
  const int s = newid % nShort, l = newid / nShort;
  const int m0 = (shortIsM ? s : l) * 256;
  const int n0 = (shortIsM ? l : s) * 256;

  // ---- staging: 4 rounds per matrix; dest chunk p = r*512+tid (16B) ----
  const ushort_t* pA[4];
  const ushort_t* pB[4];
  #pragma unroll
  for (int r = 0; r < 4; r++) {
    int p = r * 512 + tid;
    int row = p >> 3;
    int col = ((p & 7) ^ (row & 7)) * 8;
    pA[r] = A + (size_t)(m0 + row) * lda + col;
    pB[r] = B + (size_t)(n0 + row) * ldb + col;
  }

  // ---- fragment read byte-offsets (swizzled); k-half composed via XOR ----
  int aoff[8], boff[4];
  #pragma unroll
  for (int i = 0; i < 8; i++) {
    int ra = wr * 128 + i * 16 + (lane & 15);
    aoff[i] = (ra * 128 + ((lane >> 4) * 16)) ^ ((ra & 7) << 4);
  }
  #pragma unroll
  for (int j = 0; j < 4; j++) {
    int rb = wc * 64 + j * 16 + (lane & 15);
    boff[j] = (rb * 128 + ((lane >> 4) * 16)) ^ ((rb & 7) << 4);
  }

  f32x4 acc[8][4];
  #pragma unroll
  for (int i = 0; i < 8; i++)
    #pragma unroll
    for (int j = 0; j < 4; j++)
      acc[i][j] = (f32x4){0.f, 0.f, 0.f, 0.f};

  auto stage = [&](int buf, int step) {
    int sg = (step >= sps) ? ((step >= 2 * sps) ? 2 : 1) : 0;
    int ks = (step - sg * sps) << 6;
    int kA = ((sg == 0) ? kbA0 : (sg == 1) ? kbA1 : kbA2) + ks;
    int kB = ((sg == 0) ? kbB0 : (sg == 1) ? kbB1 : kbB2) + ks;
    #pragma unroll
    for (int r = 0; r < 4; r++) {
      load_lds16(pA[r] + kA, &As[buf][(r * 512 + tid) * 8]);
      load_lds16(pB[r] + kB, &Bs[buf][(r * 512 + tid) * 8]);
    }
  };

  stage(0, 0);
  __syncthreads();              // vmcnt drain -> buf0 ready

  int cur = 0;
  for (int step = 0; step < nsteps; ++step) {
    if (step + 1 < nsteps) stage(cur ^ 1, step + 1);   // loads fly over compute

    const char* Ab = (const char*)As[cur];
    const char* Bb = (const char*)Bs[cur];
    #pragma unroll
    for (int kh = 0; kh < 2; ++kh) {
      bf16x8 af[8], bfr[4];
      #pragma unroll
      for (int i = 0; i < 8; i++) af[i] = *(const bf16x8*)(Ab + (aoff[i] ^ (kh << 6)));
      #pragma unroll
      for (int j = 0; j < 4; j++) bfr[j] = *(const bf16x8*)(Bb + (boff[j] ^ (kh << 6)));
      #pragma unroll
      for (int i = 0; i < 8; i++)
        #pragma unroll
        for (int j = 0; j < 4; j++)
          acc[i][j] = __builtin_amdgcn_mfma_f32_16x16x32_bf16(af[i], bfr[j], acc[i][j], 0, 0, 0);
    }
    __syncthreads();            // drains vmcnt (next buf ready) + lgkm
    cur ^= 1;
  }

  // ---- epilogue ----
  float bv[4];
  #pragma unroll
  for (int j = 0; j < 4; j++)
    bv[j] = bias[n0 + wc * 64 + j * 16 + (lane & 15)];
  #pragma unroll
  for (int i = 0; i < 8; i++) {
    int rowb = m0 + wr * 128 + i * 16 + ((lane >> 4) << 2);
    #pragma unroll
    for (int r = 0; r < 4; r++) {
      #pragma unroll
      for (int j = 0; j < 4; j++) {
        int col = n0 + wc * 64 + j * 16 + (lane & 15);
        float v = acc[i][j][r] + bv[j];
        if (EPI == 0) {
          v = fmaxf(v, 0.f);
          ((ushort_t*)Cout)[(size_t)(rowb + r) * ldc + col] = f2bf(v);
        } else {
          ((float*)Cout)[(size_t)(rowb + r) * ldc + col] = v;
        }
      }
    }
  }
}

// ------------------------------------------------------------------
// Top-16: wave-cooperative ballot-filtered select (unchanged, verified).
// ------------------------------------------------------------------
__device__ __forceinline__ u64_t shfl_up1_u64(u64_t v) {
  uint_t lo = (uint_t)v, hi = (uint_t)(v >> 32);
  lo = __shfl_up(lo, 1, 64); hi = __shfl_up(hi, 1, 64);
  return ((u64_t)hi << 32) | lo;
}
__device__ __forceinline__ u64_t shfl_u64(u64_t v, int src) {
  uint_t lo = (uint_t)v, hi = (uint_t)(v >> 32);
  lo = __shfl(lo, src, 64); hi = __shfl(hi, src, 64);
  return ((u64_t)hi << 32) | lo;
}
__device__ __forceinline__ void insert_step(u64_t& key, u64_t cand, int lane) {
  u64_t kup = shfl_up1_u64(key);
  if (lane == 0) kup = ~0ULL;
  if (cand > key) key = (cand > kup) ? kup : cand;
}

__global__ __launch_bounds__(256) void topk_kernel(const float* __restrict__ lp,
                                                   const float* __restrict__ log_w,
                                                   float* __restrict__ out) {
  const int b = blockIdx.x;
  const int tid = threadIdx.x;
  const int w = tid >> 6, lane = tid & 63;
  const float* row = lp + (size_t)b * NCOMP;

  u64_t key = 0;
  u64_t theta = 0;

  const int base = w * 8192;
  for (int c = 0; c < 32; ++c) {
    int n0 = base + c * 256 + lane * 4;
    float4 s4 = *(const float4*)&row[n0];
    float4 w4 = *(const float4*)&log_w[n0];
    float ss[4] = {s4.x + w4.x, s4.y + w4.y, s4.z + w4.z, s4.w + w4.w};
    #pragma unroll
    for (int e = 0; e < 4; e++) {
      uint_t u = __float_as_uint(ss[e]);
      u = (u & 0x80000000u) ? ~u : (u | 0x80000000u);
      u64_t k = ((u64_t)u << 32) | (u64_t)(0xFFFFFFFFu - (uint_t)(n0 + e));
      u64_t m = __ballot(k > theta);
      if (m) {
        do {
          int src = __ffsll((long long)m) - 1;
          m &= m - 1;
          u64_t cand = shfl_u64(k, src);
          insert_step(key, cand, lane);
        } while (m);
        theta = shfl_u64(key, 15);
      }
    }
  }

  __shared__ u64_t sk[64];
  if (lane < 16) sk[w * 16 + lane] = key;
  __syncthreads();
  if (w == 0) {
    u64_t th = shfl_u64(key, 15);
    for (int t = 16; t < 64; ++t) {
      u64_t cand = sk[t];
      if (cand > th) {
        insert_step(key, cand, lane);
        th = shfl_u64(key, 15);
      }
    }
    if (lane < 16) {
      uint_t idx = 0xFFFFFFFFu - (uint_t)key;
      out[(size_t)b * KTOP + lane] = row[idx];
    }
  }
}

// ------------------------------------------------------------------
extern "C" void kernel_launch(void* const* d_in, const int* in_sizes, int n_in,
                              void* d_out, int out_size, void* d_ws, size_t ws_size,
                              hipStream_t stream) {
  const float* x     = (const float*)d_in[0];
  const float* log_w = (const float*)d_in[1];
  const float* z     = (const float*)d_in[2];
  const float* W1    = (const float*)d_in[3];
  const float* b1    = (const float*)d_in[4];
  const float* W2    = (const float*)d_in[5];
  const float* b2    = (const float*)d_in[6];
  float* out = (float*)d_out;

  char* p = (char*)d_ws;
  float* raw   = (float*)p;    p += (size_t)NCOMP * 512 * 4;   // 64MB (reused as lp)
  float* cvec  = (float*)p;    p += (size_t)NCOMP * 4;
  ushort_t* Ps = (ushort_t*)p; p += (size_t)NCOMP * 1024 * 2;  // 64MB
  ushort_t* h16= (ushort_t*)p; p += (size_t)NCOMP * 512 * 2;   // 32MB
  ushort_t* z16= (ushort_t*)p; p += (size_t)NCOMP * 128 * 2;   // 8MB
  ushort_t* W1t= (ushort_t*)p; p += (size_t)512 * 128 * 2;
  ushort_t* W2t= (ushort_t*)p; p += (size_t)512 * 512 * 2;
  ushort_t* Xs = (ushort_t*)p; p += (size_t)512 * 512 * 2;
  float* lp = raw;

  // prep
  hipLaunchKernelGGL(cast_z_kernel, dim3(NCOMP * LDIM / 1024), dim3(256), 0, stream, z, z16);
  hipLaunchKernelGGL(transpose_cast_kernel, dim3(LDIM * HDIM / 256), dim3(256), 0, stream, W1, W1t, LDIM);
  hipLaunchKernelGGL(transpose_cast_kernel, dim3(HDIM * HDIM / 256), dim3(256), 0, stream, W2, W2t, HDIM);
  hipLaunchKernelGGL(xprime_split_kernel, dim3(BROWS * DDIM / 256), dim3(256), 0, stream, x, Xs);

  // G1: h16 = relu(z16 @ W1t^T + b1)   [32768,128] x [512,128]^T
  hipLaunchKernelGGL((gemm256<0>), dim3(256), dim3(512), 0, stream,
                     z16, LDIM, W1t, LDIM, b1, h16, HDIM,
                     2, 2, 0, 0, 0, 0, 0, 0, 2, 0);
  // G2: raw = h16 @ W2t^T + b2         [32768,512] x [512,512]^T
  hipLaunchKernelGGL((gemm256<1>), dim3(256), dim3(512), 0, stream,
                     h16, HDIM, W2t, HDIM, b2, raw, HDIM,
                     8, 8, 0, 0, 0, 0, 0, 0, 2, 0);
  // params: raw -> Ps (split hi/lo), cvec
  hipLaunchKernelGGL(params_kernel, dim3(NCOMP / 4), dim3(256), 0, stream, raw, Ps, cvec);
  // G3: lp = Xs @ Ps^T + cvec  (split-bf16, A-lo dropped: uh*vh + uh*vl)
  //     K=1024: A segs {0,0} (hi,hi); B segs {0,512} (hi,lo); nt=16
  hipLaunchKernelGGL((gemm256<1>), dim3(256), dim3(512), 0, stream,
                     Xs, 512, Ps, 1024, cvec, lp, NCOMP,
                     16, 8, 0, 0, 0, 0, 512, 0, 2, 1);
  // topk
  hipLaunchKernelGGL(topk_kernel, dim3(BROWS), dim3(256), 0, stream, lp, log_w, out);
}